// Round 8
// baseline (335.826 us; speedup 1.0000x reference)
//
#include <hip/hip_runtime.h>
#include <hip/hip_bf16.h>

#define SEQ 2048
#define DIM 1024
#define NH  16
#define HD  64
#define PVSPLIT 4
#define PVCOLS (SEQ / PVSPLIT)   // 512 k-cols per pv split
#define NKB 32                   // k-blocks of 64 in pass 1

typedef __bf16 bf16_t;
typedef __bf16 bf16x4 __attribute__((ext_vector_type(4)));
typedef __bf16 bf16x8 __attribute__((ext_vector_type(8)));
typedef float  f32x4  __attribute__((ext_vector_type(4)));

#define MFMA16(a,b,c) __builtin_amdgcn_mfma_f32_16x16x32_bf16((a),(b),(c),0,0,0)

__device__ __forceinline__ void gload_lds16(const void* g, void* l) {
    __builtin_amdgcn_global_load_lds(
        (const __attribute__((address_space(1))) unsigned int*)g,
        (__attribute__((address_space(3))) unsigned int*)l, 16, 0, 0);
}

// ---------------- cos/sin tables: [2048][32] ----------------
__global__ __launch_bounds__(256) void k_tables(const float* __restrict__ invf,
                                                float* __restrict__ cosT,
                                                float* __restrict__ sinT) {
    int id = blockIdx.x * 256 + threadIdx.x;     // 65536 total
    int t = id >> 5, i = id & 31;
    float f = (float)t * invf[i];
    cosT[id] = cosf(f);
    sinT[id] = sinf(f);
}

// ---------------- f32 -> bf16 convert (x4 per thread) ----------------
__global__ __launch_bounds__(256) void k_cvt(const float* __restrict__ in,
                                             bf16_t* __restrict__ out, int n4) {
    int id = blockIdx.x * 256 + threadIdx.x;
    if (id < n4) {
        float4 v = ((const float4*)in)[id];
        bf16x4 o;
        o[0] = (bf16_t)v.x; o[1] = (bf16_t)v.y; o[2] = (bf16_t)v.z; o[3] = (bf16_t)v.w;
        ((bf16x4*)out)[id] = o;
    }
}

// ---------------- bias concat for fused QKV ----------------
__global__ __launch_bounds__(256) void k_biasqkv(const float* __restrict__ bq,
                                                 const float* __restrict__ bv,
                                                 float* __restrict__ bqkv) {
    int n = blockIdx.x * 256 + threadIdx.x;       // 3072
    bqkv[n] = (n < 1024) ? bq[n] : ((n < 2048) ? 0.0f : bv[n - 2048]);
}

// ---------------- m97-style NT GEMM: C[M][N] = A[M][K] @ W[N][K]^T + bias ----------------
__global__ __launch_bounds__(256) void gemm128(const bf16_t* __restrict__ A,
                                               const bf16_t* __restrict__ W,
                                               const float* __restrict__ bias,
                                               bf16_t* __restrict__ outBf,
                                               float* __restrict__ outF,
                                               int N, int K) {
    __shared__ __align__(16) bf16_t As[2][128 * 32];
    __shared__ __align__(16) bf16_t Bs[2][128 * 32];
    int tid = threadIdx.x, wid = tid >> 6, lane = tid & 63;
    int lrow = lane >> 4, lcol = lane & 15;
    int wr = wid >> 1, wc = wid & 1;
    int m0 = blockIdx.x * 128, n0 = blockIdx.y * 128;

    int sr = wid * 32 + (lane >> 2);
    int sc = (lane & 3) * 8;
    const bf16_t* Ag = A + (size_t)(m0 + sr) * K + sc;
    const bf16_t* Wg = W + (size_t)(n0 + sr) * K + sc;

    f32x4 acc[4][4] = {};

#define STAGE(buf, k0) do { \
        gload_lds16(Ag + (k0),          &As[buf][wid * 1024]);       \
        gload_lds16(Ag + 16 * K + (k0), &As[buf][wid * 1024 + 512]); \
        gload_lds16(Wg + (k0),          &Bs[buf][wid * 1024]);       \
        gload_lds16(Wg + 16 * K + (k0), &Bs[buf][wid * 1024 + 512]); \
    } while (0)

    STAGE(0, 0);
    __syncthreads();
    int buf = 0;
    for (int k0 = 0; k0 < K; k0 += 32) {
        if (k0 + 32 < K) STAGE(buf ^ 1, k0 + 32);
        bf16x8 af[4], bfr[4];
#pragma unroll
        for (int mi = 0; mi < 4; mi++)
            af[mi] = *(const bf16x8*)&As[buf][(wr * 64 + mi * 16 + lcol) * 32 + lrow * 8];
#pragma unroll
        for (int ni = 0; ni < 4; ni++)
            bfr[ni] = *(const bf16x8*)&Bs[buf][(wc * 64 + ni * 16 + lcol) * 32 + lrow * 8];
#pragma unroll
        for (int mi = 0; mi < 4; mi++)
#pragma unroll
            for (int ni = 0; ni < 4; ni++)
                acc[mi][ni] = MFMA16(af[mi], bfr[ni], acc[mi][ni]);
        __syncthreads();
        buf ^= 1;
    }
#undef STAGE
#pragma unroll
    for (int ni = 0; ni < 4; ni++) {
        int col = n0 + wc * 64 + ni * 16 + lcol;
        float bb = bias ? bias[col] : 0.0f;
#pragma unroll
        for (int mi = 0; mi < 4; mi++)
#pragma unroll
            for (int j = 0; j < 4; j++) {
                int row = m0 + wr * 64 + mi * 16 + lrow * 4 + j;
                float v = acc[mi][ni][j] + bb;
                if (outBf) outBf[(size_t)row * N + col] = (bf16_t)v;
                else       outF [(size_t)row * N + col] = v;
            }
    }
}

// ---------------- RoPE + scale; head-major Qh/Kh; zscale folded into K ----------------
__global__ __launch_bounds__(256) void k_rope(const bf16_t* __restrict__ QKV,
                                              const float* __restrict__ cosT,
                                              const float* __restrict__ sinT,
                                              const float* __restrict__ Zf,
                                              bf16_t* __restrict__ Qh,
                                              bf16_t* __restrict__ Kh,
                                              float* __restrict__ zsq) {
    int id = blockIdx.x * 256 + threadIdx.x;      // 2048*512
    int s = id >> 9, pp = id & 511;
    int h = pp >> 5, i = pp & 31;
    float c  = cosT[s * 32 + i];
    float sn = sinT[s * 32 + i];
    const float scale = 0.3535533905932738f;      // 64^-0.25
    size_t qb = (size_t)s * 3072 + h * HD + 2 * i;  // Q slice
    size_t kb = qb + 1024;                          // K slice
    size_t ob = ((size_t)h * SEQ + s) * HD + 2 * i; // head-major out

    float qa = (float)QKV[qb], qbv = (float)QKV[qb + 1];
    Qh[ob]     = (bf16_t)((qa * c - qbv * sn) * scale);
    Qh[ob + 1] = (bf16_t)((qa * sn + qbv * c) * scale);

    // zscale from rotated k[...,0] of this (h,s)
    float k0a = (float)QKV[(size_t)s * 3072 + 1024 + h * HD];
    float k0b = (float)QKV[(size_t)s * 3072 + 1024 + h * HD + 1];
    float ra0 = k0a * cosT[s * 32] - k0b * sinT[s * 32];
    float z = Zf[0];
    float zfac = fminf(fmaxf(log1pf(__expf(z)), 1e-5f), 1e-4f);
    float zs = (ra0 == 0.0f) ? zfac : 1.0f;

    float ka = (float)QKV[kb], kbv = (float)QKV[kb + 1];
    float ra = ka * c - kbv * sn;
    float rb = ka * sn + kbv * c;
    Kh[ob]     = (bf16_t)(ra * scale * zs);
    Kh[ob + 1] = (bf16_t)(rb * scale * zs);
    if (i == 0) zsq[h * SEQ + s] = zs * zs;
}

// ---------------- V transpose: Vt[D][S] (== head-major [NH][HD][SEQ]) ----------------
__global__ __launch_bounds__(256) void k_transpose(const bf16_t* __restrict__ QKV,
                                                   bf16_t* __restrict__ Vt) {
    __shared__ bf16_t tile[64][66];
    int t = threadIdx.x;
    int c = t & 63, r4 = t >> 6;
    int s0 = blockIdx.x * 64, d0 = blockIdx.y * 64;
#pragma unroll
    for (int i = 0; i < 16; i++) {
        int r = i * 4 + r4;
        tile[r][c] = QKV[(size_t)(s0 + r) * 3072 + 2048 + d0 + c];
    }
    __syncthreads();
#pragma unroll
    for (int i = 0; i < 16; i++) {
        int r = i * 4 + r4;   // d index within tile
        Vt[(size_t)(d0 + r) * SEQ + s0 + c] = tile[c][r];
    }
}

// ---------------- PASS 1: qk GEMM + epilogue + per-64k-block row max ----------------
// grid (NKB=32, 16, NH): x = k-block(64), y = q-block(128), z = head. 4 waves.
// Wave w computes a 64k x 32q patch: q0 = by*128 + w*32.
// Swapped MFMA(Kfrag, Qfrag): lane holds S[k = k0+mi*16+lrow*4+j][q = q0+nj*16+lcol]
// -> f32x4 store covers 4 consecutive k of one q row. No LDS, no serial chain.
__global__ __launch_bounds__(256, 2) void k_qk(const bf16_t* __restrict__ Kh,
                                               const bf16_t* __restrict__ Qh,
                                               const float* __restrict__ mask,
                                               const float* __restrict__ zsq,
                                               float* __restrict__ qk_out,
                                               float* __restrict__ tmax) {
    int tid = threadIdx.x, wid = tid >> 6, lane = tid & 63;
    int lrow = lane >> 4, lcol = lane & 15;
    int kb = blockIdx.x, h = blockIdx.z;
    int k0 = kb * 64;
    int q0 = blockIdx.y * 128 + wid * 32;

    const bf16_t* kh = Kh + (size_t)h * SEQ * HD;
    const bf16_t* qh = Qh + (size_t)h * SEQ * HD;

    bf16x8 a[4][2], b[2][2];
#pragma unroll
    for (int mi = 0; mi < 4; mi++)
#pragma unroll
        for (int ks = 0; ks < 2; ks++)
            a[mi][ks] = *(const bf16x8*)(kh + (size_t)(k0 + mi * 16 + lcol) * HD + ks * 32 + lrow * 8);
#pragma unroll
    for (int nj = 0; nj < 2; nj++)
#pragma unroll
        for (int ks = 0; ks < 2; ks++)
            b[nj][ks] = *(const bf16x8*)(qh + (size_t)(q0 + nj * 16 + lcol) * HD + ks * 32 + lrow * 8);

    f32x4 acc[4][2] = {};
#pragma unroll
    for (int mi = 0; mi < 4; mi++)
#pragma unroll
        for (int nj = 0; nj < 2; nj++) {
            acc[mi][nj] = MFMA16(a[mi][0], b[nj][0], acc[mi][nj]);
            acc[mi][nj] = MFMA16(a[mi][1], b[nj][1], acc[mi][nj]);
        }

    float* qkb = qk_out + (size_t)h * SEQ * SEQ;
    const float* zrow = zsq + h * SEQ;
    float tm[2] = {-1e30f, -1e30f};
#pragma unroll
    for (int mi = 0; mi < 4; mi++) {
        int k4 = k0 + mi * 16 + lrow * 4;
        f32x4 zv = *(const f32x4*)(zrow + k4);
#pragma unroll
        for (int nj = 0; nj < 2; nj++) {
            int q = q0 + nj * 16 + lcol;
            f32x4 mv = *(const f32x4*)(mask + (size_t)q * SEQ + k4);
            f32x4 v;
#pragma unroll
            for (int j = 0; j < 4; j++) {
                v[j] = fmaf(mv[j], zv[j], acc[mi][nj][j]);
                tm[nj] = fmaxf(tm[nj], v[j]);
            }
            *(f32x4*)(qkb + (size_t)q * SEQ + k4) = v;
        }
    }
    // reduce each tm over the 4 lanes sharing q (lrow bits)
#pragma unroll
    for (int nj = 0; nj < 2; nj++) {
        tm[nj] = fmaxf(tm[nj], __shfl_xor(tm[nj], 16));
        tm[nj] = fmaxf(tm[nj], __shfl_xor(tm[nj], 32));
    }
    if (lrow == 0) {
#pragma unroll
        for (int nj = 0; nj < 2; nj++) {
            int q = q0 + nj * 16 + lcol;
            tmax[((size_t)h * SEQ + q) * NKB + kb] = tm[nj];
        }
    }
}

// ---------------- PASS 1.5: rowmax over 32 k-block partials ----------------
__global__ __launch_bounds__(256) void k_rowmax(const float* __restrict__ tmax,
                                                float* __restrict__ rowM) {
    int row = blockIdx.x * 256 + threadIdx.x;     // NH*SEQ rows
    const float* tp = tmax + (size_t)row * NKB;
    float mx = -1e30f;
#pragma unroll
    for (int i = 0; i < NKB / 4; i++) {
        f32x4 v = *(const f32x4*)(tp + i * 4);
        mx = fmaxf(mx, fmaxf(fmaxf(v[0], v[1]), fmaxf(v[2], v[3])));
    }
    rowM[row] = mx;
}

// ---------------- PASS 2: PV with known row max; streaming qk re-read ----------------
// grid (32, NH, PVSPLIT): x = q-block(64), y = head, z = k-split. 4 waves, 16 q-rows each.
// Lane loads exp(qk[q=lcol][k]) directly in B-fragment layout (k = ks*32+lrow*8..+7):
// no LDS, no shuffles, no rescale. Partials (same m) combine by plain summation.
__global__ __launch_bounds__(256, 2) void k_pv(const float* __restrict__ qk_out,
                                               const bf16_t* __restrict__ Vt,
                                               const float* __restrict__ rowM,
                                               float* __restrict__ Opart,
                                               float* __restrict__ Lpart) {
    int tid = threadIdx.x, wid = tid >> 6, lane = tid & 63;
    int lrow = lane >> 4, lcol = lane & 15;
    int h = blockIdx.y, sp = blockIdx.z;
    int q0 = blockIdx.x * 64 + wid * 16;
    int kbase = sp * PVCOLS;

    float m = rowM[(size_t)h * SEQ + q0 + lcol];
    float l = 0.f;
    f32x4 acc[4] = {};
    const float* qkrow = qk_out + (size_t)h * SEQ * SEQ + (size_t)(q0 + lcol) * SEQ;
    const bf16_t* vthead = Vt + (size_t)h * HD * SEQ;

    for (int kc = kbase; kc < kbase + PVCOLS; kc += 128) {
        bf16x8 pa[4];
#pragma unroll
        for (int ks = 0; ks < 4; ks++) {
            const float* src = qkrow + kc + ks * 32 + lrow * 8;
            f32x4 e0 = *(const f32x4*)(src);
            f32x4 e1 = *(const f32x4*)(src + 4);
            bf16x8 pk;
#pragma unroll
            for (int j = 0; j < 4; j++) {
                float x0 = __expf(e0[j] - m);
                float x1 = __expf(e1[j] - m);
                l += x0 + x1;
                pk[j] = (bf16_t)x0;
                pk[j + 4] = (bf16_t)x1;
            }
            pa[ks] = pk;
        }
#pragma unroll
        for (int ks = 0; ks < 4; ks++) {
#pragma unroll
            for (int ng = 0; ng < 4; ng++) {
                bf16x8 bv = *(const bf16x8*)(vthead + (size_t)(ng * 16 + lcol) * SEQ + kc + ks * 32 + lrow * 8);
                acc[ng] = MFMA16(bv, pa[ks], acc[ng]);
            }
        }
    }
    // store f32 partials: O[q=lcol][ng*16+lrow*4+j]
#pragma unroll
    for (int ng = 0; ng < 4; ng++) {
        size_t idx = (((size_t)h * SEQ + q0 + lcol) * PVSPLIT + sp) * HD + ng * 16 + lrow * 4;
        *(f32x4*)(Opart + idx) = acc[ng];
    }
    l += __shfl_xor(l, 16);
    l += __shfl_xor(l, 32);
    if (lane < 16) {
        Lpart[((size_t)h * SEQ + q0 + lane) * PVSPLIT + sp] = l;
    }
}

// ---------------- PV combine: exact sums (same m), normalize, write WVb ----------------
__global__ __launch_bounds__(256) void k_comb(const float* __restrict__ Opart,
                                              const float* __restrict__ Lpart,
                                              bf16_t* __restrict__ wv) {
    int gid = blockIdx.x * 256 + threadIdx.x;     // NH*SEQ*64
    int rowIdx = gid >> 6, d = gid & 63;
    const float* lp = Lpart + (size_t)rowIdx * PVSPLIT;
    float L = 0.f, O = 0.f;
    const float* ob = Opart + (size_t)rowIdx * PVSPLIT * HD + d;
#pragma unroll
    for (int s = 0; s < PVSPLIT; s++) {
        L += lp[s];
        O += ob[(size_t)s * HD];
    }
    int h = rowIdx >> 11, row = rowIdx & (SEQ - 1);
    wv[(size_t)row * DIM + h * HD + d] = (bf16_t)(O / L);
}

extern "C" void kernel_launch(void* const* d_in, const int* in_sizes, int n_in,
                              void* d_out, int out_size, void* d_ws, size_t ws_size,
                              hipStream_t stream) {
    const float* x    = (const float*)d_in[0];
    const float* mask = (const float*)d_in[1];
    const float* Wq   = (const float*)d_in[2];
    const float* bq   = (const float*)d_in[3];
    const float* Wk   = (const float*)d_in[4];
    const float* Wv   = (const float*)d_in[5];
    const float* bv   = (const float*)d_in[6];
    const float* Wo   = (const float*)d_in[7];
    const float* bo   = (const float*)d_in[8];
    const float* Zf   = (const float*)d_in[9];
    const float* invf = (const float*)d_in[10];

    char* ws = (char*)d_ws;
    size_t off = 0;
    auto alloc = [&](size_t bytes) -> char* {
        char* p = ws + off;
        off += (bytes + 255) & ~(size_t)255;
        return p;
    };
    float*  cosT  = (float*)alloc(65536 * 4);
    float*  sinT  = (float*)alloc(65536 * 4);
    bf16_t* Xb    = (bf16_t*)alloc((size_t)SEQ * DIM * 2);
    bf16_t* Wqkvb = (bf16_t*)alloc((size_t)3 * DIM * DIM * 2);
    bf16_t* Wob   = (bf16_t*)alloc((size_t)DIM * DIM * 2);
    float*  bqkv  = (float*)alloc(3072 * 4);
    bf16_t* QKV   = (bf16_t*)alloc((size_t)SEQ * 3 * DIM * 2);
    bf16_t* Qhp   = (bf16_t*)alloc((size_t)SEQ * DIM * 2);
    bf16_t* Khp   = (bf16_t*)alloc((size_t)SEQ * DIM * 2);
    bf16_t* Vt    = (bf16_t*)alloc((size_t)DIM * SEQ * 2);
    float*  zsq   = (float*)alloc((size_t)NH * SEQ * 4);
    float*  tmax  = (float*)alloc((size_t)NH * SEQ * NKB * 4);
    float*  rowM  = (float*)alloc((size_t)NH * SEQ * 4);
    float*  Opart = (float*)alloc((size_t)NH * SEQ * PVSPLIT * HD * 4);
    float*  Lpart = (float*)alloc((size_t)NH * SEQ * PVSPLIT * 4);
    bf16_t* WVb   = (bf16_t*)alloc((size_t)SEQ * DIM * 2);

    float* outp = (float*)d_out;
    float* qkp  = outp + (size_t)SEQ * DIM;   // out is 2048*1024, then qk 16*2048*2048

    k_tables<<<256, 256, 0, stream>>>(invf, cosT, sinT);
    k_cvt<<<(SEQ * DIM / 4 + 255) / 256, 256, 0, stream>>>(x,  Xb, SEQ * DIM / 4);
    k_cvt<<<(DIM * DIM / 4 + 255) / 256, 256, 0, stream>>>(Wq, Wqkvb,                 DIM * DIM / 4);
    k_cvt<<<(DIM * DIM / 4 + 255) / 256, 256, 0, stream>>>(Wk, Wqkvb + DIM * DIM,     DIM * DIM / 4);
    k_cvt<<<(DIM * DIM / 4 + 255) / 256, 256, 0, stream>>>(Wv, Wqkvb + 2 * DIM * DIM, DIM * DIM / 4);
    k_cvt<<<(DIM * DIM / 4 + 255) / 256, 256, 0, stream>>>(Wo, Wob, DIM * DIM / 4);
    k_biasqkv<<<12, 256, 0, stream>>>(bq, bv, bqkv);

    // fused QKV projection: [2048][3072]
    gemm128<<<dim3(SEQ / 128, 3072 / 128), 256, 0, stream>>>(Xb, Wqkvb, bqkv, QKV, nullptr, 3072, DIM);

    k_rope<<<(SEQ * 512) / 256, 256, 0, stream>>>(QKV, cosT, sinT, Zf, Qhp, Khp, zsq);
    k_transpose<<<dim3(SEQ / 64, NH), 256, 0, stream>>>(QKV, Vt);

    // Pass 1: qk materialization + block row-max partials
    k_qk<<<dim3(NKB, SEQ / 128, NH), 256, 0, stream>>>(Khp, Qhp, mask, zsq, qkp, tmax);
    // Pass 1.5: true row max
    k_rowmax<<<(NH * SEQ) / 256, 256, 0, stream>>>(tmax, rowM);
    // Pass 2: PV with known max, k-split x4
    k_pv<<<dim3(SEQ / 64, NH, PVSPLIT), 256, 0, stream>>>(qkp, Vt, rowM, Opart, Lpart);
    k_comb<<<(NH * SEQ * HD) / 256, 256, 0, stream>>>(Opart, Lpart, WVb);

    // output projection (f32 out)
    gemm128<<<dim3(SEQ / 128, DIM / 128), 256, 0, stream>>>(WVb, Wob, bo, nullptr, outp, DIM, DIM);
}